// Round 1
// baseline (764.538 us; speedup 1.0000x reference)
//
#include <hip/hip_runtime.h>

#define NB 8
#define NS 2048
#define NH 768
#define NPOS (NB*NS)

// ---------------- Kernel A: build V = U * diag((-i)^popcount(j)) ----------------
// One block, threads 0..15 each simulate one basis column of the 2-layer
// StronglyEntanglingLayers circuit (Rot gates + CNOT rings r=1, r=2).
__global__ void build_V_kernel(const float* __restrict__ wts,
                               float* __restrict__ Vre, float* __restrict__ Vim) {
  int j = threadIdx.x;
  if (j >= 16) return;
  float ar[16], ai[16];
#pragma unroll
  for (int i = 0; i < 16; i++) { ar[i] = (i == j) ? 1.f : 0.f; ai[i] = 0.f; }
#pragma unroll
  for (int l = 0; l < 2; l++) {
    // per-qubit Rot(phi, theta, omega); wire q acts on bit (3-q) (wire 0 = MSB)
#pragma unroll
    for (int q = 0; q < 4; q++) {
      float phi = wts[(l*4+q)*3+0];
      float th  = wts[(l*4+q)*3+1];
      float om  = wts[(l*4+q)*3+2];
      float ct = cosf(0.5f*th), st = sinf(0.5f*th);
      float sm = 0.5f*(phi+om), df = 0.5f*(phi-om);
      float cs = cosf(sm), ss = sinf(sm), cd = cosf(df), sd = sinf(df);
      // R = [[a,b],[c,d]], a=e^{-i sm} ct, b=-e^{i df} st, c=e^{-i df} st, d=e^{i sm} ct
      float Ar =  cs*ct, Ai = -ss*ct;
      float Br = -cd*st, Bi = -sd*st;
      float Cr =  cd*st, Ci = -sd*st;
      float Dr =  cs*ct, Di =  ss*ct;
      int pb = 1 << (3-q);
#pragma unroll
      for (int b0 = 0; b0 < 16; b0++) {
        if (b0 & pb) continue;
        int b1 = b0 | pb;
        float xr = ar[b0], xi = ai[b0], yr = ar[b1], yi = ai[b1];
        ar[b0] = Ar*xr - Ai*xi + Br*yr - Bi*yi;
        ai[b0] = Ar*xi + Ai*xr + Br*yi + Bi*yr;
        ar[b1] = Cr*xr - Ci*xi + Dr*yr - Di*yi;
        ai[b1] = Cr*xi + Ci*xr + Dr*yi + Di*yr;
      }
    }
    // entangler: apply CNOT(i,(i+r)%4) for i=0..3 in order
    const int r = (l == 0) ? 1 : 2;
#pragma unroll
    for (int i2 = 0; i2 < 4; i2++) {
      int cb = 1 << (3-i2);
      int tb = 1 << (3-((i2+r)&3));
#pragma unroll
      for (int b0 = 0; b0 < 16; b0++) {
        if ((b0 & cb) && !(b0 & tb)) {
          int b1 = b0 | tb;
          float tr = ar[b0], ti = ai[b0];
          ar[b0] = ar[b1]; ai[b0] = ai[b1];
          ar[b1] = tr;     ai[b1] = ti;
        }
      }
    }
  }
  // fold psi0 phase (-i)^popcount(j) into column j
  int pc = __popc((unsigned)j) & 3;
#pragma unroll
  for (int i = 0; i < 16; i++) {
    float vr = ar[i], vi = ai[i], orr, oi;
    if      (pc == 0) { orr =  vr; oi =  vi; }
    else if (pc == 1) { orr =  vi; oi = -vr; }
    else if (pc == 2) { orr = -vr; oi = -vi; }
    else              { orr = -vi; oi =  vr; }
    Vre[i*16+j] = orr;
    Vim[i*16+j] = oi;
  }
}

// ---------------- Kernel B: Q/K projection + VQC evaluation ----------------
// One wave per position: 768-long dots for 8 outputs (lane-strided, W in
// 9-padded LDS -> 2-way conflicts = free), butterfly reduce, then lanes 0-15
// do Q's VQC and lanes 16-31 do K's VQC concurrently (real 16x16 matvecs).
__global__ __launch_bounds__(256) void proj_vqc_kernel(
    const float* __restrict__ E, const float* __restrict__ Wq, const float* __restrict__ bq,
    const float* __restrict__ Wk, const float* __restrict__ bk,
    const float* __restrict__ Vre, const float* __restrict__ Vim,
    float* __restrict__ Qv, float* __restrict__ Kv) {
  __shared__ float Wl[768*9];       // [elem][w0..3=Wq, w4..7=Wk], pad 9
  __shared__ float Vsh[2][16*17];   // re/im, pad 17
  int tid = threadIdx.x;
  for (int idx = tid; idx < 768*8; idx += 256) {
    int e = idx >> 3, w = idx & 7;
    Wl[e*9+w] = (w < 4) ? Wq[w*768+e] : Wk[(w-4)*768+e];
  }
  for (int idx = tid; idx < 256; idx += 256) {
    int i = idx >> 4, jj = idx & 15;
    Vsh[0][i*17+jj] = Vre[idx];
    Vsh[1][i*17+jj] = Vim[idx];
  }
  __syncthreads();
  float bqr0=bq[0], bqr1=bq[1], bqr2=bq[2], bqr3=bq[3];
  float bkr0=bk[0], bkr1=bk[1], bkr2=bk[2], bkr3=bk[3];
  int lane = tid & 63;
  int wid  = blockIdx.x*4 + (tid >> 6);
  int nw   = gridDim.x*4;
  int grp  = lane >> 4;   // 0 -> Q, 1 -> K, 2/3 idle in VQC phase
  int i    = lane & 15;
  for (int pos = wid; pos < NPOS; pos += nw) {
    const float* er = E + (size_t)pos*768;
    float part[8] = {0.f,0.f,0.f,0.f,0.f,0.f,0.f,0.f};
#pragma unroll
    for (int k2 = 0; k2 < 12; k2++) {
      float ev = er[lane + 64*k2];
      int base = (lane + 64*k2)*9;
#pragma unroll
      for (int w = 0; w < 8; w++) part[w] += ev * Wl[base+w];
    }
#pragma unroll
    for (int w = 0; w < 8; w++) {
      float v = part[w];
      v += __shfl_xor(v, 32); v += __shfl_xor(v, 16); v += __shfl_xor(v, 8);
      v += __shfl_xor(v, 4);  v += __shfl_xor(v, 2);  v += __shfl_xor(v, 1);
      part[w] = v;
    }
    if (grp < 2) {
      float a0,a1,a2,a3;
      if (grp == 0) { a0=part[0]+bqr0; a1=part[1]+bqr1; a2=part[2]+bqr2; a3=part[3]+bqr3; }
      else          { a0=part[4]+bkr0; a1=part[5]+bkr1; a2=part[6]+bkr2; a3=part[7]+bkr3; }
      float c0=cosf(0.5f*a0), s0=sinf(0.5f*a0);
      float c1=cosf(0.5f*a1), s1=sinf(0.5f*a1);
      float c2=cosf(0.5f*a2), s2=sinf(0.5f*a2);
      float c3=cosf(0.5f*a3), s3=sinf(0.5f*a3);
      float m[16];
#pragma unroll
      for (int j2 = 0; j2 < 16; j2++) {
        float f0 = (j2 & 8) ? s0 : c0;
        float f1 = (j2 & 4) ? s1 : c1;
        float f2 = (j2 & 2) ? s2 : c2;
        float f3 = (j2 & 1) ? s3 : c3;
        m[j2] = f0*f1*f2*f3;
      }
      float re = 0.f, im = 0.f;
#pragma unroll
      for (int j2 = 0; j2 < 16; j2++) {
        re += Vsh[0][i*17+j2]*m[j2];
        im += Vsh[1][i*17+j2]*m[j2];
      }
      float pr = re*re + im*im;
      float r0 = (i & 8) ? -pr : pr;
      float r1 = (i & 4) ? -pr : pr;
      float r2 = (i & 2) ? -pr : pr;
      float r3 = (i & 1) ? -pr : pr;
#pragma unroll
      for (int off = 8; off >= 1; off >>= 1) {
        r0 += __shfl_xor(r0, off);
        r1 += __shfl_xor(r1, off);
        r2 += __shfl_xor(r2, off);
        r3 += __shfl_xor(r3, off);
      }
      if (i == 0) {
        float* dst = (grp == 0 ? Qv : Kv) + (size_t)pos*4;
        dst[0]=r0; dst[1]=r1; dst[2]=r2; dst[3]=r3;
      }
    }
  }
}

// ---------------- Kernel C: fused flash-style attention ----------------
// Block = (64 s-rows x 256 h-cols) of one batch; loop t in chunks of 32.
// Scores bounded in [-4,4] (PauliZ expvals) -> exp directly, no max-sub.
#define TS 64
#define TC 32
#define EROW 260   // 256 + 4 pad (keeps 16B alignment, breaks bank stride)

__global__ __launch_bounds__(256) void attn_kernel(
    const float* __restrict__ E, const float* __restrict__ Qv,
    const float* __restrict__ Kv, float* __restrict__ out) {
  int hblk = blockIdx.x;   // 0..2
  int sblk = blockIdx.y;   // 0..31
  int b    = blockIdx.z;   // 0..7
  int tid  = threadIdx.x;
  __shared__ float Esh[TC*EROW];   // 33280 B
  __shared__ float Pt[TC*TS];      //  8192 B  (transposed: [tt][s])
  __shared__ float qvsh[TS*5];     //  1280 B  (pad 5)
  __shared__ float kvsh[TC*4];     //   512 B
  __shared__ float denacc[4*TS];   //  1024 B
  denacc[tid] = 0.f;
  {
    int s = tid >> 2, w = tid & 3;
    qvsh[s*5+w] = Qv[((size_t)(b*NS + sblk*TS))*4 + tid];
  }
  const float* Eb  = E  + (size_t)b*NS*NH + hblk*256;
  const float* Kvb = Kv + (size_t)b*NS*4;
  int ps = tid & 63, pg = tid >> 6;        // P-phase mapping
  int hc = tid & 15, sr = tid >> 4;        // GEMM mapping: 4 rows x 16 cols(strided)
  float acc[4][16];
#pragma unroll
  for (int r = 0; r < 4; r++)
#pragma unroll
    for (int c = 0; c < 16; c++) acc[r][c] = 0.f;

  for (int tc = 0; tc < NS; tc += TC) {
    __syncthreads();
    if (tid < TC*4) kvsh[tid] = Kvb[tc*4 + tid];
#pragma unroll
    for (int k2 = 0; k2 < 8; k2++) {
      int f4  = tid + 256*k2;
      int row = f4 >> 6, c4 = f4 & 63;
      float4 v = *(const float4*)(Eb + (size_t)(tc+row)*NH + c4*4);
      *(float4*)(&Esh[row*EROW + c4*4]) = v;
    }
    __syncthreads();
    // P-tile: p = exp(qv . kv); each thread: one s, 8 tt's
    float q0=qvsh[ps*5+0], q1=qvsh[ps*5+1], q2=qvsh[ps*5+2], q3=qvsh[ps*5+3];
    float psum = 0.f;
#pragma unroll
    for (int j2 = 0; j2 < 8; j2++) {
      int tt = pg*8 + j2;
      float arg = q0*kvsh[tt*4+0] + q1*kvsh[tt*4+1] + q2*kvsh[tt*4+2] + q3*kvsh[tt*4+3];
      float p = __expf(arg);
      Pt[tt*TS + ps] = p;
      psum += p;
    }
    denacc[tid] += psum;
    __syncthreads();
    // rank-1 update GEMM: acc[4][16] += P[4] x E[16]
#pragma unroll 8
    for (int tt = 0; tt < TC; ++tt) {
      float4 p4 = *(const float4*)(&Pt[tt*TS + sr*4]);
      const float* erow = &Esh[tt*EROW + hc*4];
#pragma unroll
      for (int cc = 0; cc < 4; ++cc) {
        float4 e4 = *(const float4*)(erow + cc*64);
        acc[0][cc*4+0] += p4.x*e4.x; acc[0][cc*4+1] += p4.x*e4.y; acc[0][cc*4+2] += p4.x*e4.z; acc[0][cc*4+3] += p4.x*e4.w;
        acc[1][cc*4+0] += p4.y*e4.x; acc[1][cc*4+1] += p4.y*e4.y; acc[1][cc*4+2] += p4.y*e4.z; acc[1][cc*4+3] += p4.y*e4.w;
        acc[2][cc*4+0] += p4.z*e4.x; acc[2][cc*4+1] += p4.z*e4.y; acc[2][cc*4+2] += p4.z*e4.z; acc[2][cc*4+3] += p4.z*e4.w;
        acc[3][cc*4+0] += p4.w*e4.x; acc[3][cc*4+1] += p4.w*e4.y; acc[3][cc*4+2] += p4.w*e4.z; acc[3][cc*4+3] += p4.w*e4.w;
      }
    }
  }
  __syncthreads();
  float* ob = out + ((size_t)(b*NS + sblk*TS))*NH + hblk*256;
#pragma unroll
  for (int r = 0; r < 4; r++) {
    int s = sr*4 + r;
    float d = denacc[s] + denacc[64+s] + denacc[128+s] + denacc[192+s];
    float invd = 1.0f / d;
#pragma unroll
    for (int cc = 0; cc < 4; cc++) {
      float4 o;
      o.x = acc[r][cc*4+0]*invd; o.y = acc[r][cc*4+1]*invd;
      o.z = acc[r][cc*4+2]*invd; o.w = acc[r][cc*4+3]*invd;
      *(float4*)(&ob[(size_t)s*NH + hc*4 + cc*64]) = o;
    }
  }
}

extern "C" void kernel_launch(void* const* d_in, const int* in_sizes, int n_in,
                              void* d_out, int out_size, void* d_ws, size_t ws_size,
                              hipStream_t stream) {
  const float* E   = (const float*)d_in[0];
  const float* Wq  = (const float*)d_in[1];
  const float* bq  = (const float*)d_in[2];
  const float* Wk  = (const float*)d_in[3];
  const float* bk  = (const float*)d_in[4];
  const float* wts = (const float*)d_in[5];
  float* ws  = (float*)d_ws;
  float* Vre = ws;                   // 256 floats
  float* Vim = ws + 256;             // 256 floats
  float* Qv  = ws + 512;             // NPOS*4
  float* Kv  = ws + 512 + NPOS*4;    // NPOS*4
  float* out = (float*)d_out;

  build_V_kernel<<<1, 64, 0, stream>>>(wts, Vre, Vim);
  proj_vqc_kernel<<<256, 256, 0, stream>>>(E, Wq, bq, Wk, bk, Vre, Vim, Qv, Kv);
  attn_kernel<<<dim3(3, 32, 8), 256, 0, stream>>>(E, Qv, Kv, out);
}

// Round 2
// 456.397 us; speedup vs baseline: 1.6752x; 1.6752x over previous
//
#include <hip/hip_runtime.h>

#define NB 8
#define NS 2048
#define NH 768
#define NPOS (NB*NS)

typedef short short8 __attribute__((ext_vector_type(8)));
typedef float floatx4 __attribute__((ext_vector_type(4)));

// ---------------- Kernel A: build V = U * diag((-i)^popcount(j)) ----------------
__global__ void build_V_kernel(const float* __restrict__ wts,
                               float* __restrict__ Vre, float* __restrict__ Vim) {
  int j = threadIdx.x;
  if (j >= 16) return;
  float ar[16], ai[16];
#pragma unroll
  for (int i = 0; i < 16; i++) { ar[i] = (i == j) ? 1.f : 0.f; ai[i] = 0.f; }
#pragma unroll
  for (int l = 0; l < 2; l++) {
#pragma unroll
    for (int q = 0; q < 4; q++) {
      float phi = wts[(l*4+q)*3+0];
      float th  = wts[(l*4+q)*3+1];
      float om  = wts[(l*4+q)*3+2];
      float ct = cosf(0.5f*th), st = sinf(0.5f*th);
      float sm = 0.5f*(phi+om), df = 0.5f*(phi-om);
      float cs = cosf(sm), ss = sinf(sm), cd = cosf(df), sd = sinf(df);
      float Ar =  cs*ct, Ai = -ss*ct;
      float Br = -cd*st, Bi = -sd*st;
      float Cr =  cd*st, Ci = -sd*st;
      float Dr =  cs*ct, Di =  ss*ct;
      int pb = 1 << (3-q);
#pragma unroll
      for (int b0 = 0; b0 < 16; b0++) {
        if (b0 & pb) continue;
        int b1 = b0 | pb;
        float xr = ar[b0], xi = ai[b0], yr = ar[b1], yi = ai[b1];
        ar[b0] = Ar*xr - Ai*xi + Br*yr - Bi*yi;
        ai[b0] = Ar*xi + Ai*xr + Br*yi + Bi*yr;
        ar[b1] = Cr*xr - Ci*xi + Dr*yr - Di*yi;
        ai[b1] = Cr*xi + Ci*xr + Dr*yi + Di*yr;
      }
    }
    const int r = (l == 0) ? 1 : 2;
#pragma unroll
    for (int i2 = 0; i2 < 4; i2++) {
      int cb = 1 << (3-i2);
      int tb = 1 << (3-((i2+r)&3));
#pragma unroll
      for (int b0 = 0; b0 < 16; b0++) {
        if ((b0 & cb) && !(b0 & tb)) {
          int b1 = b0 | tb;
          float tr = ar[b0], ti = ai[b0];
          ar[b0] = ar[b1]; ai[b0] = ai[b1];
          ar[b1] = tr;     ai[b1] = ti;
        }
      }
    }
  }
  int pc = __popc((unsigned)j) & 3;
#pragma unroll
  for (int i = 0; i < 16; i++) {
    float vr = ar[i], vi = ai[i], orr, oi;
    if      (pc == 0) { orr =  vr; oi =  vi; }
    else if (pc == 1) { orr =  vi; oi = -vr; }
    else if (pc == 2) { orr = -vr; oi = -vi; }
    else              { orr = -vi; oi =  vr; }
    Vre[i*16+j] = orr;
    Vim[i*16+j] = oi;
  }
}

// ---------------- Kernel B: Q/K projection + VQC evaluation ----------------
__global__ __launch_bounds__(256) void proj_vqc_kernel(
    const float* __restrict__ E, const float* __restrict__ Wq, const float* __restrict__ bq,
    const float* __restrict__ Wk, const float* __restrict__ bk,
    const float* __restrict__ Vre, const float* __restrict__ Vim,
    float* __restrict__ Qv, float* __restrict__ Kv) {
  __shared__ float Wl[768*9];
  __shared__ float Vsh[2][16*17];
  int tid = threadIdx.x;
  for (int idx = tid; idx < 768*8; idx += 256) {
    int e = idx >> 3, w = idx & 7;
    Wl[e*9+w] = (w < 4) ? Wq[w*768+e] : Wk[(w-4)*768+e];
  }
  if (tid < 256) {
    int i = tid >> 4, jj = tid & 15;
    Vsh[0][i*17+jj] = Vre[tid];
    Vsh[1][i*17+jj] = Vim[tid];
  }
  __syncthreads();
  float bqr0=bq[0], bqr1=bq[1], bqr2=bq[2], bqr3=bq[3];
  float bkr0=bk[0], bkr1=bk[1], bkr2=bk[2], bkr3=bk[3];
  int lane = tid & 63;
  int wid  = blockIdx.x*4 + (tid >> 6);
  int nw   = gridDim.x*4;
  int grp  = lane >> 4;
  int i    = lane & 15;
  for (int pos = wid; pos < NPOS; pos += nw) {
    const float* er = E + (size_t)pos*768;
    float part[8] = {0.f,0.f,0.f,0.f,0.f,0.f,0.f,0.f};
#pragma unroll
    for (int k2 = 0; k2 < 12; k2++) {
      float ev = er[lane + 64*k2];
      int base = (lane + 64*k2)*9;
#pragma unroll
      for (int w = 0; w < 8; w++) part[w] += ev * Wl[base+w];
    }
#pragma unroll
    for (int w = 0; w < 8; w++) {
      float v = part[w];
      v += __shfl_xor(v, 32); v += __shfl_xor(v, 16); v += __shfl_xor(v, 8);
      v += __shfl_xor(v, 4);  v += __shfl_xor(v, 2);  v += __shfl_xor(v, 1);
      part[w] = v;
    }
    if (grp < 2) {
      float a0,a1,a2,a3;
      if (grp == 0) { a0=part[0]+bqr0; a1=part[1]+bqr1; a2=part[2]+bqr2; a3=part[3]+bqr3; }
      else          { a0=part[4]+bkr0; a1=part[5]+bkr1; a2=part[6]+bkr2; a3=part[7]+bkr3; }
      float c0=cosf(0.5f*a0), s0=sinf(0.5f*a0);
      float c1=cosf(0.5f*a1), s1=sinf(0.5f*a1);
      float c2=cosf(0.5f*a2), s2=sinf(0.5f*a2);
      float c3=cosf(0.5f*a3), s3=sinf(0.5f*a3);
      float m[16];
#pragma unroll
      for (int j2 = 0; j2 < 16; j2++) {
        float f0 = (j2 & 8) ? s0 : c0;
        float f1 = (j2 & 4) ? s1 : c1;
        float f2 = (j2 & 2) ? s2 : c2;
        float f3 = (j2 & 1) ? s3 : c3;
        m[j2] = f0*f1*f2*f3;
      }
      float re = 0.f, im = 0.f;
#pragma unroll
      for (int j2 = 0; j2 < 16; j2++) {
        re += Vsh[0][i*17+j2]*m[j2];
        im += Vsh[1][i*17+j2]*m[j2];
      }
      float pr = re*re + im*im;
      float r0 = (i & 8) ? -pr : pr;
      float r1 = (i & 4) ? -pr : pr;
      float r2 = (i & 2) ? -pr : pr;
      float r3 = (i & 1) ? -pr : pr;
#pragma unroll
      for (int off = 8; off >= 1; off >>= 1) {
        r0 += __shfl_xor(r0, off);
        r1 += __shfl_xor(r1, off);
        r2 += __shfl_xor(r2, off);
        r3 += __shfl_xor(r3, off);
      }
      if (i == 0) {
        float* dst = (grp == 0 ? Qv : Kv) + (size_t)pos*4;
        dst[0]=r0; dst[1]=r1; dst[2]=r2; dst[3]=r3;
      }
    }
  }
}

// ---------------- Kernel C: fused flash attention, split-bf16 MFMA ----------------
// Block tile: 128 s x 128 h, K-chunks of 32 t. P = exp(Qv.Kv) in [e^-4, e^4].
// P,E split into hi+lo bf16 (truncation); 3 MFMA passes hi*hi+hi*lo+lo*hi.
#define BS 128
#define BH 128
#define TK 32

__device__ __forceinline__ unsigned pack_bf16(unsigned b0, unsigned b1) {
  return (b0 >> 16) | (b1 & 0xFFFF0000u);
}

__global__ __launch_bounds__(256) void attn_kernel(
    const float* __restrict__ E, const float* __restrict__ Qv,
    const float* __restrict__ Kv, float* __restrict__ out) {
  int sblk = blockIdx.x;   // 0..15
  int hblk = blockIdx.y;   // 0..5
  int b    = blockIdx.z;   // 0..7
  int tid  = threadIdx.x;
  int lane = tid & 63;
  int w    = tid >> 6;

  __shared__ __align__(16) unsigned short sAhi[BS*TK];  // P hi, [s][t]
  __shared__ __align__(16) unsigned short sAlo[BS*TK];  // P lo
  __shared__ __align__(16) unsigned short sBhi[BH*TK];  // E hi, [h][t]
  __shared__ __align__(16) unsigned short sBlo[BH*TK];  // E lo
  __shared__ float kvf[2][TK][4];
  __shared__ float denp[BS*4];
  __shared__ float dfin[BS];

  const float* Eb  = E  + (size_t)b*NS*NH + hblk*BH;
  const float* Kvb = Kv + (size_t)b*NS*4;

  // P-gen task mapping: task = tid + 256*r -> s = task>>2 (0..127), q = task&3
  int s0_ = tid >> 2, q0_ = tid & 3;
  int s1_ = (tid + 256) >> 2, q1_ = q0_;
  floatx4 qv0, qv1;
  {
    const float4 t0 = *(const float4*)&Qv[((size_t)(b*NS + sblk*BS) + s0_)*4];
    const float4 t1 = *(const float4*)&Qv[((size_t)(b*NS + sblk*BS) + s1_)*4];
    qv0 = floatx4{t0.x, t0.y, t0.z, t0.w};
    qv1 = floatx4{t1.x, t1.y, t1.z, t1.w};
  }
  float den0 = 0.f, den1 = 0.f;

  // accumulators: wave tile 64x64 = 4x4 subtiles of 16x16
  int sh = w & 1, hh = w >> 1;
  floatx4 acc[4][4];
#pragma unroll
  for (int i = 0; i < 4; i++)
#pragma unroll
    for (int jt = 0; jt < 4; jt++) acc[i][jt] = floatx4{0.f,0.f,0.f,0.f};

  // prefetch kv chunk 0
  if (tid < TK*4) kvf[0][tid>>2][tid&3] = Kvb[tid];

  int m16 = lane & 15, q16 = lane >> 4;

  for (int tc = 0; tc < NS; tc += TK) {
    int cb = (tc / TK) & 1;
    __syncthreads();   // prev MFMA done reading LDS; kv[cb] visible

    // --- kv prefetch for next chunk ---
    if (tc + TK < NS && tid < TK*4)
      kvf[cb^1][tid>>2][tid&3] = Kvb[(size_t)(tc+TK)*4 + tid];

    // --- stage E chunk [32 t][128 h] -> sB[h][t] hi/lo (transposed, split) ---
#pragma unroll
    for (int r2 = 0; r2 < 2; r2++) {
      int task = tid + 256*r2;
      int q2 = task >> 7, h2 = task & 127;
      unsigned hi4[4], lo4[4];
#pragma unroll
      for (int jp = 0; jp < 4; jp++) {
        float ea = Eb[(size_t)(tc + q2*8 + 2*jp    )*NH + h2];
        float eb2 = Eb[(size_t)(tc + q2*8 + 2*jp + 1)*NH + h2];
        unsigned ba = __float_as_uint(ea), bb = __float_as_uint(eb2);
        unsigned ha = ba & 0xFFFF0000u,  hb2 = bb & 0xFFFF0000u;
        float la = ea - __uint_as_float(ha);
        float lb = eb2 - __uint_as_float(hb2);
        hi4[jp] = pack_bf16(ha, hb2);
        lo4[jp] = pack_bf16(__float_as_uint(la), __float_as_uint(lb));
      }
      *(uint4*)&sBhi[h2*TK + q2*8] = make_uint4(hi4[0],hi4[1],hi4[2],hi4[3]);
      *(uint4*)&sBlo[h2*TK + q2*8] = make_uint4(lo4[0],lo4[1],lo4[2],lo4[3]);
    }

    // --- P-gen: p = exp(qv.kv), split, write A-layout [s][t] ---
#pragma unroll
    for (int r = 0; r < 2; r++) {
      int s = r ? s1_ : s0_;
      int q = r ? q1_ : q0_;
      floatx4 qv = r ? qv1 : qv0;
      unsigned hi4[4], lo4[4];
      float dsum = 0.f;
#pragma unroll
      for (int jp = 0; jp < 4; jp++) {
        float4 ka = *(const float4*)&kvf[cb][q*8 + 2*jp][0];
        float4 kb = *(const float4*)&kvf[cb][q*8 + 2*jp + 1][0];
        float arga = qv.x*ka.x + qv.y*ka.y + qv.z*ka.z + qv.w*ka.w;
        float argb = qv.x*kb.x + qv.y*kb.y + qv.z*kb.z + qv.w*kb.w;
        float pa = __expf(arga), pb = __expf(argb);
        dsum += pa + pb;
        unsigned bpa = __float_as_uint(pa), bpb = __float_as_uint(pb);
        unsigned hpa = bpa & 0xFFFF0000u,  hpb = bpb & 0xFFFF0000u;
        float lpa = pa - __uint_as_float(hpa);
        float lpb = pb - __uint_as_float(hpb);
        hi4[jp] = pack_bf16(hpa, hpb);
        lo4[jp] = pack_bf16(__float_as_uint(lpa), __float_as_uint(lpb));
      }
      if (r) den1 += dsum; else den0 += dsum;
      *(uint4*)&sAhi[s*TK + q*8] = make_uint4(hi4[0],hi4[1],hi4[2],hi4[3]);
      *(uint4*)&sAlo[s*TK + q*8] = make_uint4(lo4[0],lo4[1],lo4[2],lo4[3]);
    }

    __syncthreads();   // A,B tiles ready

    // --- MFMA: wave (sh,hh) computes 64x64 via 4x4 tiles of 16x16x32 ---
    short8 bh_[4], bl_[4];
#pragma unroll
    for (int jt = 0; jt < 4; jt++) {
      int hrow = hh*64 + jt*16 + m16;
      bh_[jt] = __builtin_bit_cast(short8, *(const uint4*)&sBhi[hrow*TK + q16*8]);
      bl_[jt] = __builtin_bit_cast(short8, *(const uint4*)&sBlo[hrow*TK + q16*8]);
    }
#pragma unroll
    for (int i = 0; i < 4; i++) {
      int srow = sh*64 + i*16 + m16;
      short8 ah = __builtin_bit_cast(short8, *(const uint4*)&sAhi[srow*TK + q16*8]);
      short8 al = __builtin_bit_cast(short8, *(const uint4*)&sAlo[srow*TK + q16*8]);
#pragma unroll
      for (int jt = 0; jt < 4; jt++) {
        acc[i][jt] = __builtin_amdgcn_mfma_f32_16x16x32_bf16(ah, bl_[jt], acc[i][jt], 0, 0, 0);
        acc[i][jt] = __builtin_amdgcn_mfma_f32_16x16x32_bf16(al, bh_[jt], acc[i][jt], 0, 0, 0);
        acc[i][jt] = __builtin_amdgcn_mfma_f32_16x16x32_bf16(ah, bh_[jt], acc[i][jt], 0, 0, 0);
      }
    }
  }

  // --- denominator reduce ---
  __syncthreads();
  denp[s0_*4 + q0_] = den0;
  denp[s1_*4 + q1_] = den1;
  __syncthreads();
  if (tid < BS) {
    dfin[tid] = denp[tid*4] + denp[tid*4+1] + denp[tid*4+2] + denp[tid*4+3];
  }
  __syncthreads();

  // --- epilogue: C/D layout col=lane&15, row=(lane>>4)*4+reg ---
  float* ob = out + ((size_t)(b*NS + sblk*BS))*NH + hblk*BH;
#pragma unroll
  for (int i = 0; i < 4; i++) {
#pragma unroll
    for (int reg = 0; reg < 4; reg++) {
      int row = q16*4 + reg;
      int s_loc = sh*64 + i*16 + row;
      float invd = 1.0f / dfin[s_loc];
#pragma unroll
      for (int jt = 0; jt < 4; jt++) {
        int h_loc = hh*64 + jt*16 + m16;
        ob[(size_t)s_loc*NH + h_loc] = acc[i][jt][reg] * invd;
      }
    }
  }
}

extern "C" void kernel_launch(void* const* d_in, const int* in_sizes, int n_in,
                              void* d_out, int out_size, void* d_ws, size_t ws_size,
                              hipStream_t stream) {
  const float* E   = (const float*)d_in[0];
  const float* Wq  = (const float*)d_in[1];
  const float* bq  = (const float*)d_in[2];
  const float* Wk  = (const float*)d_in[3];
  const float* bk  = (const float*)d_in[4];
  const float* wts = (const float*)d_in[5];
  float* ws  = (float*)d_ws;
  float* Vre = ws;
  float* Vim = ws + 256;
  float* Qv  = ws + 512;
  float* Kv  = ws + 512 + NPOS*4;
  float* out = (float*)d_out;

  build_V_kernel<<<1, 64, 0, stream>>>(wts, Vre, Vim);
  proj_vqc_kernel<<<1024, 256, 0, stream>>>(E, Wq, bq, Wk, bk, Vre, Vim, Qv, Kv);
  attn_kernel<<<dim3(16, 6, 8), 256, 0, stream>>>(E, Qv, Kv, out);
}